// Round 5
// baseline (89865.009 us; speedup 1.0000x reference)
//
#include <hip/hip_runtime.h>
#include <hip/hip_cooperative_groups.h>
#include <stdint.h>

namespace cg = cooperative_groups;

#define N_NEUR  1024
#define N_INP   256
#define N_OUTC  32
#define T_STEPS 500
#define BATCH   64
#define N_DEL   8
#define NB      (N_NEUR*BATCH)     // 65536, layout [n][b], b fastest
#define HSLOTS  130                // ring: reads are ages 2..129, write age 1 -> disjoint
#define CAP     320                // per-(o,d) record capacity (mean 128, sigma ~10.6)

// ---------------------------------------------------------------------------
// inpT[t][c][b] = inputs[b][t][c]
__global__ __launch_bounds__(256) void transpose_inp(const float* __restrict__ inp,
                                                     float* __restrict__ inpT) {
    __shared__ float L[N_INP * 64];
    int t = blockIdx.x;
    int tid = threadIdx.x;                   // = c
    for (int b = 0; b < 64; ++b) {
        float v = inp[((size_t)b * T_STEPS + t) * N_INP + tid];
        L[tid * 64 + (b ^ (tid & 63))] = v;
    }
    __syncthreads();
    int lane = tid & 63;
    int wv   = tid >> 6;
    for (int cc = 0; cc < 64; ++cc) {
        int c = cc * 4 + wv;
        inpT[((size_t)t * N_INP + c) * 64 + lane] = L[c * 64 + (lane ^ (c & 63))];
    }
}

// w_inT[n][c] = w_in[c][n]
__global__ __launch_bounds__(256) void transpose_win(const float* __restrict__ w_in,
                                                     float* __restrict__ w_inT) {
    int i = blockIdx.x * 256 + threadIdx.x;  // 262144
    int n = i >> 8, c = i & 255;
    w_inT[i] = w_in[(size_t)c * N_NEUR + n];
}

// ---------------------------------------------------------------------------
// CSR build: for each (o,d), list of {G = sign[e]*|w[e][o]|, e*64} where
// dmap[d][e][o] == 1. Exactly 1024 records total per o (one delay per synapse).
__global__ __launch_bounds__(64) void build_csr(const float* __restrict__ w,
                                                const float* __restrict__ signs,
                                                const float* __restrict__ dmap,
                                                uint2* __restrict__ recs,
                                                int* __restrict__ cnt) {
    int o = blockIdx.x * 64 + threadIdx.x;   // 16 blocks x 64 lanes
    for (int d = 0; d < N_DEL; ++d) {
        int c = 0;
        uint2* seg = recs + ((size_t)o * N_DEL + d) * CAP;
        for (int e = 0; e < N_NEUR; ++e) {
            float m = dmap[((size_t)d * N_NEUR + e) * N_NEUR + o];  // coalesced over o
            if (m != 0.f) {
                float G = signs[e] * fabsf(w[(size_t)e * N_NEUR + o]);
                if (c < CAP) seg[c] = make_uint2(__float_as_uint(G), (unsigned)(e * 64));
                ++c;
            }
        }
        cnt[o * N_DEL + d] = (c < CAP) ? c : CAP;
    }
}

// ---------------------------------------------------------------------------
// Persistent cooperative kernel: all 500 steps, 1 grid.sync per step.
// Block = o (GEMM role) = n (pointwise role). Phase t does GEMM(t) and
// pointwise(t-1) concurrently:
//   GEMM(t) reads hist slots of age 2..129 (min delay 1 -> t-2 and older);
//   pointwise(t-1) writes slot age 1 -> disjoint (ring 130).
//   syn buffers ping-pong on t&1 -> no intra-phase conflict.
__global__ __launch_bounds__(256, 4) void persistent(
        const uint2* __restrict__ recs, const int* __restrict__ cnt,
        const int* __restrict__ delays, const float* __restrict__ inpT,
        const float* __restrict__ w_inT, const float* __restrict__ p,
        float* __restrict__ histc, float* __restrict__ mem,
        float* __restrict__ wp_arr, float* __restrict__ syn0,
        float* __restrict__ syn1, unsigned long long* __restrict__ spk) {
    cg::grid_group grid = cg::this_grid();
    int blk  = blockIdx.x;                               // o / n
    int lane = threadIdx.x & 63;                         // b
    int wv   = __builtin_amdgcn_readfirstlane(threadIdx.x >> 6);
    __shared__ float Lg[4 * 64];   // GEMM reduce
    __shared__ float Lp[4 * 64];   // pointwise h1 reduce
    int dl[N_DEL];
#pragma unroll
    for (int d = 0; d < N_DEL; ++d)
        dl[d] = __builtin_amdgcn_readfirstlane(delays[d]);
    float pn = p[blk];                                   // uniform -> s_load
    float pd = (pn < 0.f) ? 1.f : 0.f;

    for (int t = 0; t <= T_STEPS; ++t) {
        // ---- GEMM(t): syn_p[b][o=blk] = sum over this wave's 2 delay lists
        if (t < T_STEPS) {
            float acc = 0.f;
#pragma unroll
            for (int s = 0; s < 2; ++s) {
                int d   = wv * 2 + s;
                int tau = t - 1 - dl[d];
                if (tau >= 0) {
                    const float* hb = histc + (size_t)(tau % HSLOTS) * NB;
                    const uint2* R  = recs + ((size_t)blk * N_DEL + d) * CAP;
                    int c = cnt[blk * N_DEL + d];        // uniform
                    int k = 0;
                    for (; k + 4 <= c; k += 4) {         // 32B record bursts (s_load)
                        uint2 r0 = R[k], r1 = R[k+1], r2 = R[k+2], r3 = R[k+3];
                        acc = fmaf(__uint_as_float(r0.x), hb[r0.y + lane], acc);
                        acc = fmaf(__uint_as_float(r1.x), hb[r1.y + lane], acc);
                        acc = fmaf(__uint_as_float(r2.x), hb[r2.y + lane], acc);
                        acc = fmaf(__uint_as_float(r3.x), hb[r3.y + lane], acc);
                    }
                    for (; k < c; ++k) {
                        uint2 r = R[k];
                        acc = fmaf(__uint_as_float(r.x), hb[r.y + lane], acc);
                    }
                }
            }
            Lg[wv * 64 + lane] = acc;
        }
        __syncthreads();
        if (t < T_STEPS && wv == 0) {
            float syn = Lg[lane] + Lg[64 + lane] + Lg[128 + lane] + Lg[192 + lane];
            float* sb = (t & 1) ? syn1 : syn0;
            sb[blk * 64 + lane] = syn;
        }
        // ---- pointwise(t-1): n = blk; h1 on the fly (c split over 4 waves)
        if (t >= 1) {
            int s = t - 1;
            float hp = 0.f;
            const float* ib = inpT + (size_t)s * (N_INP * 64)
                            + (size_t)(wv * 64) * 64 + lane;
            const float* wr = w_inT + blk * N_INP + wv * 64;   // uniform
#pragma unroll 8
            for (int c2 = 0; c2 < 64; ++c2)
                hp = fmaf(ib[(size_t)c2 * 64], wr[c2], hp);
            Lp[wv * 64 + lane] = hp;
        }
        __syncthreads();
        if (t >= 1 && wv == 0) {
            int s = t - 1;
            float h1 = Lp[lane] + Lp[64 + lane] + Lp[128 + lane] + Lp[192 + lane];
            const float* sbr = (s & 1) ? syn1 : syn0;
            float syn = sbr[blk * 64 + lane];
            int i = blk * 64 + lane;
            float m = mem[i];
            float w = wp_arr[i];
            float out = (m - 1.f > 0.f) ? 1.f : 0.f;
            w = w * 0.95f + out * pn * (1.f + pd * w);
            wp_arr[i] = w;
            histc[(size_t)(s % HSLOTS) * NB + i] = out * (1.f + w);
            mem[i] = 0.9f * m + h1 + syn - out;
            unsigned long long mask = __ballot(out > 0.f);
            if (lane == 0) spk[(size_t)s * N_NEUR + blk] = mask;
        }
        grid.sync();
    }
}

// ---------------------------------------------------------------------------
// h2[t][b][o] = sum_n spk_bit(t,n,b) * w_out[n][o]
__global__ __launch_bounds__(256) void h2_gemm(const unsigned long long* __restrict__ spk,
                                               const float* __restrict__ w_out,
                                               float* __restrict__ h2) {
    int t = blockIdx.x;
    int lane = threadIdx.x & 63;     // = b
    int wv   = threadIdx.x >> 6;
    int o0 = wv * 8;
    float acc[8];
#pragma unroll
    for (int j = 0; j < 8; ++j) acc[j] = 0.f;
    for (int n = 0; n < N_NEUR; ++n) {
        unsigned long long mask = spk[(size_t)t * N_NEUR + n];   // uniform
        float s = (float)((mask >> lane) & 1ULL);
        const float* wr = w_out + n * N_OUTC + o0;               // uniform
#pragma unroll
        for (int j = 0; j < 8; ++j) acc[j] = fmaf(s, wr[j], acc[j]);
    }
#pragma unroll
    for (int j = 0; j < 8; ++j)
        h2[((size_t)t * BATCH + lane) * N_OUTC + o0 + j] = acc[j];
}

// out[b][t][o] : leaky-integrator scan over h2
__global__ __launch_bounds__(256) void out_scan(const float* __restrict__ h2,
                                                float* __restrict__ out) {
    int tid = blockIdx.x * 256 + threadIdx.x;   // 2048 = 64b * 32o
    int o = tid & 31;
    int b = tid >> 5;
    float acc = 0.f;
    for (int t = 0; t < T_STEPS; ++t) {
        acc = 0.9f * acc + h2[((size_t)t * BATCH + b) * N_OUTC + o];
        out[((size_t)b * T_STEPS + t) * N_OUTC + o] = acc;
    }
}

// ---------------------------------------------------------------------------
extern "C" void kernel_launch(void* const* d_in, const int* in_sizes, int n_in,
                              void* d_out, int out_size, void* d_ws, size_t ws_size,
                              hipStream_t stream) {
    (void)in_sizes; (void)n_in; (void)out_size; (void)ws_size;
    const float* inputs = (const float*)d_in[0];
    const float* w      = (const float*)d_in[1];
    const float* w_in   = (const float*)d_in[2];
    const float* w_out  = (const float*)d_in[3];
    const float* signs  = (const float*)d_in[4];
    const float* p      = (const float*)d_in[5];
    const float* dmap   = (const float*)d_in[6];
    const int*   delays = (const int*)d_in[7];
    float* out = (float*)d_out;

    // workspace layout (~93.6 MiB total)
    float* ws    = (float*)d_ws;
    float* inpT  = ws;                                    //  8,192,000 f
    float* w_inT = inpT + (size_t)T_STEPS * N_INP * 64;   //    262,144 f
    float* histc = w_inT + (size_t)N_NEUR * N_INP;        //  8,519,680 f
    float* syn0  = histc + (size_t)HSLOTS * NB;           //     65,536 f
    float* syn1  = syn0 + NB;                             //     65,536 f
    float* mem   = syn1 + NB;                             //     65,536 f
    float* wp    = mem + NB;                              //     65,536 f
    float* h2    = wp + NB;                               //  1,024,000 f
    int*   cnt   = (int*)(h2 + (size_t)T_STEPS * BATCH * N_OUTC);  // 8192 i
    uint2* recs  = (uint2*)(cnt + N_NEUR * N_DEL);        //  2,621,440 uint2
    unsigned long long* spk =
        (unsigned long long*)(recs + (size_t)N_NEUR * N_DEL * CAP); // 512,000 ull

    hipMemsetAsync(histc, 0, sizeof(float) * (size_t)HSLOTS * NB, stream);
    hipMemsetAsync(mem, 0, sizeof(float) * (size_t)2 * NB, stream);  // mem+wp adjacent

    transpose_inp<<<T_STEPS, 256, 0, stream>>>(inputs, inpT);
    transpose_win<<<(N_NEUR * N_INP) / 256, 256, 0, stream>>>(w_in, w_inT);
    build_csr<<<16, 64, 0, stream>>>(w, signs, dmap, recs, cnt);

    void* args[] = {(void*)&recs, (void*)&cnt, (void*)&delays, (void*)&inpT,
                    (void*)&w_inT, (void*)&p, (void*)&histc, (void*)&mem,
                    (void*)&wp, (void*)&syn0, (void*)&syn1, (void*)&spk};
    hipLaunchCooperativeKernel((const void*)persistent, dim3(1024), dim3(256),
                               args, 0, stream);

    h2_gemm<<<T_STEPS, 256, 0, stream>>>(spk, w_out, h2);
    out_scan<<<8, 256, 0, stream>>>(h2, out);
}

// Round 6
// 14054.495 us; speedup vs baseline: 6.3940x; 6.3940x over previous
//
#include <hip/hip_runtime.h>
#include <stdint.h>

#define N_NEUR  1024
#define N_INP   256
#define N_OUTC  32
#define T_STEPS 500
#define BATCH   64
#define N_DEL   8
#define NB      (N_NEUR*BATCH)     // 65536, layout [n][b], b fastest
#define HSLOTS  130                // ring: writes age 0..1, reads ages 2..129 -> disjoint
#define CAP     320                // per-(o,d) record capacity (mean 128, sigma ~10.6)

// ---------------------------------------------------------------------------
// inpT[t][c][b] = inputs[b][t][c]
__global__ __launch_bounds__(256) void transpose_inp(const float* __restrict__ inp,
                                                     float* __restrict__ inpT) {
    __shared__ float L[N_INP * 64];
    int t = blockIdx.x;
    int tid = threadIdx.x;                   // = c
    for (int b = 0; b < 64; ++b) {
        float v = inp[((size_t)b * T_STEPS + t) * N_INP + tid];
        L[tid * 64 + (b ^ (tid & 63))] = v;
    }
    __syncthreads();
    int lane = tid & 63;
    int wv   = tid >> 6;
    for (int cc = 0; cc < 64; ++cc) {
        int c = cc * 4 + wv;
        inpT[((size_t)t * N_INP + c) * 64 + lane] = L[c * 64 + (lane ^ (c & 63))];
    }
}

// w_inT[n][c] = w_in[c][n]
__global__ __launch_bounds__(256) void transpose_win(const float* __restrict__ w_in,
                                                     float* __restrict__ w_inT) {
    int i = blockIdx.x * 256 + threadIdx.x;  // 262144
    int n = i >> 8, c = i & 255;
    w_inT[i] = w_in[(size_t)c * N_NEUR + n];
}

// ---------------------------------------------------------------------------
// CSR build: for each (o,d), list of {G = sign[e]*|w[e][o]|, e*64} where
// dmap[d][e][o] == 1. Exactly 1024 records total per o (one-hot over d).
__global__ __launch_bounds__(64) void build_csr(const float* __restrict__ w,
                                                const float* __restrict__ signs,
                                                const float* __restrict__ dmap,
                                                uint2* __restrict__ recs,
                                                int* __restrict__ cnt) {
    int o = blockIdx.x * 64 + threadIdx.x;   // 16 blocks x 64 lanes
    for (int d = 0; d < N_DEL; ++d) {
        int c = 0;
        uint2* seg = recs + ((size_t)o * N_DEL + d) * CAP;
        for (int e = 0; e < N_NEUR; ++e) {
            float m = dmap[((size_t)d * N_NEUR + e) * N_NEUR + o];  // coalesced over o
            if (m != 0.f) {
                float G = signs[e] * fabsf(w[(size_t)e * N_NEUR + o]);
                if (c < CAP) seg[c] = make_uint2(__float_as_uint(G), (unsigned)(e * 64));
                ++c;
            }
        }
        cnt[o * N_DEL + d] = (c < CAP) ? c : CAP;
    }
}

// ---------------------------------------------------------------------------
// Two simulation steps per launch. Block = o (GEMM) = n (pointwise); syn never
// leaves the block, so the only cross-block dependency is hist, whose newest
// read age is 2 -> both steps' hist reads were written by PREVIOUS launches.
// Kernel boundary supplies cross-XCD coherence (no grid.sync).
__global__ __launch_bounds__(256) void step_pair(int t0,
        const uint2* __restrict__ recs, const int* __restrict__ cnt,
        const int* __restrict__ delays, const float* __restrict__ inpT,
        const float* __restrict__ w_inT, const float* __restrict__ p,
        float* __restrict__ histc, float* __restrict__ mem,
        float* __restrict__ wp_arr, unsigned long long* __restrict__ spk) {
    __shared__ uint2 Lrec[N_NEUR];   // 8 KB: this o's full record list, d-major
    __shared__ int   off[N_DEL + 1];
    __shared__ float Lg[4 * 64];     // GEMM partials
    __shared__ float Lp[4 * 64];     // h1 partials
    int blk  = blockIdx.x;           // o = n
    int tid  = threadIdx.x;
    int lane = tid & 63;             // b
    int wv   = __builtin_amdgcn_readfirstlane(tid >> 6);

    if (tid == 0) {
        int s = 0;
        for (int d = 0; d < N_DEL; ++d) { off[d] = s; s += cnt[blk * N_DEL + d]; }
        off[N_DEL] = s;
    }
    __syncthreads();
    // stage records packed d-major into LDS (coalesced 8B/thread)
    for (int d = 0; d < N_DEL; ++d) {
        const uint2* R = recs + ((size_t)blk * N_DEL + d) * CAP;
        int base = off[d], n = off[d + 1] - base;
        for (int k = tid; k < n; k += 256) Lrec[base + k] = R[k];
    }
    int d0 = wv * 2, d1 = wv * 2 + 1;
    int dl0 = __builtin_amdgcn_readfirstlane(delays[d0]);
    int dl1 = __builtin_amdgcn_readfirstlane(delays[d1]);
    float pn = p[blk];
    float pd = (pn < 0.f) ? 1.f : 0.f;
    __syncthreads();

#pragma unroll
    for (int sidx = 0; sidx < 2; ++sidx) {
        int s = t0 + sidx;
        // ---- GEMM(s): this wave's two delay segments, records from LDS
        float acc0 = 0.f, acc1 = 0.f;
#pragma unroll
        for (int seg = 0; seg < 2; ++seg) {
            int d   = seg ? d1 : d0;
            int dl  = seg ? dl1 : dl0;
            int tau = s - 1 - dl;
            if (tau >= 0) {
                const float* hb = histc + (size_t)(tau % HSLOTS) * NB;
                int kb = off[d], ke = off[d + 1];
                int k = kb;
                for (; k + 8 <= ke; k += 8) {
                    uint2 r0 = Lrec[k],     r1 = Lrec[k + 1];
                    uint2 r2 = Lrec[k + 2], r3 = Lrec[k + 3];
                    uint2 r4 = Lrec[k + 4], r5 = Lrec[k + 5];
                    uint2 r6 = Lrec[k + 6], r7 = Lrec[k + 7];
                    float v0 = hb[r0.y + lane], v1 = hb[r1.y + lane];
                    float v2 = hb[r2.y + lane], v3 = hb[r3.y + lane];
                    float v4 = hb[r4.y + lane], v5 = hb[r5.y + lane];
                    float v6 = hb[r6.y + lane], v7 = hb[r7.y + lane];
                    acc0 = fmaf(__uint_as_float(r0.x), v0, acc0);
                    acc1 = fmaf(__uint_as_float(r1.x), v1, acc1);
                    acc0 = fmaf(__uint_as_float(r2.x), v2, acc0);
                    acc1 = fmaf(__uint_as_float(r3.x), v3, acc1);
                    acc0 = fmaf(__uint_as_float(r4.x), v4, acc0);
                    acc1 = fmaf(__uint_as_float(r5.x), v5, acc1);
                    acc0 = fmaf(__uint_as_float(r6.x), v6, acc0);
                    acc1 = fmaf(__uint_as_float(r7.x), v7, acc1);
                }
                for (; k < ke; ++k) {
                    uint2 r = Lrec[k];
                    acc0 = fmaf(__uint_as_float(r.x), hb[r.y + lane], acc0);
                }
            }
        }
        Lg[wv * 64 + lane] = acc0 + acc1;
        // ---- h1(s) partial: c in [wv*64, wv*64+64)
        {
            float hp = 0.f;
            const float* ib = inpT + (size_t)s * (N_INP * 64)
                            + (size_t)(wv * 64) * 64 + lane;
            const float* wr = w_inT + blk * N_INP + wv * 64;   // uniform -> s_load
#pragma unroll 8
            for (int c2 = 0; c2 < 64; ++c2)
                hp = fmaf(ib[(size_t)c2 * 64], wr[c2], hp);
            Lp[wv * 64 + lane] = hp;
        }
        __syncthreads();
        // ---- pointwise(s): intra-block, wave 0
        if (wv == 0) {
            float syn = Lg[lane] + Lg[64 + lane] + Lg[128 + lane] + Lg[192 + lane];
            float h1  = Lp[lane] + Lp[64 + lane] + Lp[128 + lane] + Lp[192 + lane];
            int i = blk * 64 + lane;
            float m = mem[i];
            float w = wp_arr[i];
            float out = (m - 1.f > 0.f) ? 1.f : 0.f;
            w = w * 0.95f + out * pn * (1.f + pd * w);
            wp_arr[i] = w;
            histc[(size_t)(s % HSLOTS) * NB + i] = out * (1.f + w);
            mem[i] = 0.9f * m + h1 + syn - out;
            unsigned long long mask = __ballot(out > 0.f);
            if (lane == 0) spk[(size_t)s * N_NEUR + blk] = mask;
        }
        __syncthreads();   // Lg/Lp reuse in next sidx
    }
}

// ---------------------------------------------------------------------------
// h2[t][b][o] = sum_n spk_bit(t,n,b) * w_out[n][o]
__global__ __launch_bounds__(256) void h2_gemm(const unsigned long long* __restrict__ spk,
                                               const float* __restrict__ w_out,
                                               float* __restrict__ h2) {
    int t = blockIdx.x;
    int lane = threadIdx.x & 63;     // = b
    int wv   = threadIdx.x >> 6;
    int o0 = wv * 8;
    float acc[8];
#pragma unroll
    for (int j = 0; j < 8; ++j) acc[j] = 0.f;
    for (int n = 0; n < N_NEUR; ++n) {
        unsigned long long mask = spk[(size_t)t * N_NEUR + n];   // uniform
        float s = (float)((mask >> lane) & 1ULL);
        const float* wr = w_out + n * N_OUTC + o0;               // uniform
#pragma unroll
        for (int j = 0; j < 8; ++j) acc[j] = fmaf(s, wr[j], acc[j]);
    }
#pragma unroll
    for (int j = 0; j < 8; ++j)
        h2[((size_t)t * BATCH + lane) * N_OUTC + o0 + j] = acc[j];
}

// out[b][t][o] : leaky-integrator scan over h2
__global__ __launch_bounds__(256) void out_scan(const float* __restrict__ h2,
                                                float* __restrict__ out) {
    int tid = blockIdx.x * 256 + threadIdx.x;   // 2048 = 64b * 32o
    int o = tid & 31;
    int b = tid >> 5;
    float acc = 0.f;
    for (int t = 0; t < T_STEPS; ++t) {
        acc = 0.9f * acc + h2[((size_t)t * BATCH + b) * N_OUTC + o];
        out[((size_t)b * T_STEPS + t) * N_OUTC + o] = acc;
    }
}

// ---------------------------------------------------------------------------
extern "C" void kernel_launch(void* const* d_in, const int* in_sizes, int n_in,
                              void* d_out, int out_size, void* d_ws, size_t ws_size,
                              hipStream_t stream) {
    (void)in_sizes; (void)n_in; (void)out_size; (void)ws_size;
    const float* inputs = (const float*)d_in[0];
    const float* w      = (const float*)d_in[1];
    const float* w_in   = (const float*)d_in[2];
    const float* w_out  = (const float*)d_in[3];
    const float* signs  = (const float*)d_in[4];
    const float* p      = (const float*)d_in[5];
    const float* dmap   = (const float*)d_in[6];
    const int*   delays = (const int*)d_in[7];
    float* out = (float*)d_out;

    // workspace layout (~97 MiB total, well under proven 120.6 MiB)
    float* ws    = (float*)d_ws;
    float* inpT  = ws;                                    //  8,192,000 f
    float* w_inT = inpT + (size_t)T_STEPS * N_INP * 64;   //    262,144 f
    float* histc = w_inT + (size_t)N_NEUR * N_INP;        //  8,519,680 f
    float* mem   = histc + (size_t)HSLOTS * NB;           //     65,536 f
    float* wp    = mem + NB;                              //     65,536 f
    float* h2    = wp + NB;                               //  1,024,000 f
    int*   cnt   = (int*)(h2 + (size_t)T_STEPS * BATCH * N_OUTC);  // 8192 i
    uint2* recs  = (uint2*)(cnt + N_NEUR * N_DEL);        //  2,621,440 uint2
    unsigned long long* spk =
        (unsigned long long*)(recs + (size_t)N_NEUR * N_DEL * CAP); // 512,000 ull

    hipMemsetAsync(histc, 0, sizeof(float) * (size_t)HSLOTS * NB, stream);
    hipMemsetAsync(mem, 0, sizeof(float) * (size_t)2 * NB, stream);  // mem+wp adjacent

    transpose_inp<<<T_STEPS, 256, 0, stream>>>(inputs, inpT);
    transpose_win<<<(N_NEUR * N_INP) / 256, 256, 0, stream>>>(w_in, w_inT);
    build_csr<<<16, 64, 0, stream>>>(w, signs, dmap, recs, cnt);

    for (int t0 = 0; t0 < T_STEPS; t0 += 2)
        step_pair<<<N_NEUR, 256, 0, stream>>>(t0, recs, cnt, delays, inpT,
                                              w_inT, p, histc, mem, wp, spk);

    h2_gemm<<<T_STEPS, 256, 0, stream>>>(spk, w_out, h2);
    out_scan<<<8, 256, 0, stream>>>(h2, out);
}

// Round 7
// 12715.690 us; speedup vs baseline: 7.0673x; 1.1053x over previous
//
#include <hip/hip_runtime.h>
#include <stdint.h>

#define N_NEUR  1024
#define N_INP   256
#define N_OUTC  32
#define T_STEPS 500
#define BATCH   64
#define N_DEL   8
#define NB      (N_NEUR*BATCH)     // 65536, layout [n][b], b fastest
#define HSLOTS  130                // ring: writes age 0..1, reads ages 2..129 -> disjoint
#define CAP     320                // per-(o,d) record capacity (mean 128, sigma ~10.6)
#define LREC_MAX 1152              // >= 1024 + 8*3 padding

// ---------------------------------------------------------------------------
// inpT[t][c][b] = inputs[b][t][c]
__global__ __launch_bounds__(256) void transpose_inp(const float* __restrict__ inp,
                                                     float* __restrict__ inpT) {
    __shared__ float L[N_INP * 64];
    int t = blockIdx.x;
    int tid = threadIdx.x;                   // = c
    for (int b = 0; b < 64; ++b) {
        float v = inp[((size_t)b * T_STEPS + t) * N_INP + tid];
        L[tid * 64 + (b ^ (tid & 63))] = v;
    }
    __syncthreads();
    int lane = tid & 63;
    int wv   = tid >> 6;
    for (int cc = 0; cc < 64; ++cc) {
        int c = cc * 4 + wv;
        inpT[((size_t)t * N_INP + c) * 64 + lane] = L[c * 64 + (lane ^ (c & 63))];
    }
}

// w_inT[n][c] = w_in[c][n]
__global__ __launch_bounds__(256) void transpose_win(const float* __restrict__ w_in,
                                                     float* __restrict__ w_inT) {
    int i = blockIdx.x * 256 + threadIdx.x;  // 262144
    int n = i >> 8, c = i & 255;
    w_inT[i] = w_in[(size_t)c * N_NEUR + n];
}

// ---------------------------------------------------------------------------
// CSR build: for each (o,d), list of {G = sign[e]*|w[e][o]|, e*64} where
// dmap[d][e][o] == 1. Padded to a multiple of 4 with zero-records (G=0 -> inert).
__global__ __launch_bounds__(64) void build_csr(const float* __restrict__ w,
                                                const float* __restrict__ signs,
                                                const float* __restrict__ dmap,
                                                uint2* __restrict__ recs,
                                                int* __restrict__ cnt) {
    int o = blockIdx.x * 64 + threadIdx.x;   // 16 blocks x 64 lanes
    for (int d = 0; d < N_DEL; ++d) {
        int c = 0;
        uint2* seg = recs + ((size_t)o * N_DEL + d) * CAP;
        for (int e = 0; e < N_NEUR; ++e) {
            float m = dmap[((size_t)d * N_NEUR + e) * N_NEUR + o];  // coalesced over o
            if (m != 0.f) {
                float G = signs[e] * fabsf(w[(size_t)e * N_NEUR + o]);
                if (c < CAP) seg[c] = make_uint2(__float_as_uint(G), (unsigned)(e * 64));
                ++c;
            }
        }
        if (c > CAP) c = CAP;
        int c4 = (c + 3) & ~3;                // pad to multiple of 4
        for (; c < c4; ++c) seg[c] = make_uint2(0u, 0u);
        cnt[o * N_DEL + d] = c4;
    }
}

// ---------------------------------------------------------------------------
// Two simulation steps per launch. Block = o (GEMM) = n (pointwise); syn never
// leaves the block, so the only cross-block dependency is hist, whose newest
// read age is 2 -> both steps' hist reads were written by PREVIOUS launches.
// Kernel boundary supplies cross-XCD coherence.
// Gather uses quarter-wave float4 loads: lane=(q,bq), record k+q, bytes
// [bq*16, bq*16+16) of the 256B segment -> 4x fewer VMEM instructions.
__global__ __launch_bounds__(256) void step_pair(int t0,
        const uint2* __restrict__ recs, const int* __restrict__ cnt,
        const int* __restrict__ delays, const float* __restrict__ inpT,
        const float* __restrict__ w_inT, const float* __restrict__ p,
        float* __restrict__ histc, float* __restrict__ mem,
        float* __restrict__ wp_arr, unsigned long long* __restrict__ spk) {
    __shared__ uint2 Lrec[LREC_MAX]; // ~9 KB: this o's record list, d-major, padded
    __shared__ int   off[N_DEL + 1];
    __shared__ float Lg[4 * 64];     // GEMM partials
    __shared__ float Lp[4 * 64];     // h1 partials
    int blk  = blockIdx.x;           // o = n
    int tid  = threadIdx.x;
    int lane = tid & 63;             // b
    int wv   = __builtin_amdgcn_readfirstlane(tid >> 6);

    if (tid == 0) {
        int s = 0;
        for (int d = 0; d < N_DEL; ++d) { off[d] = s; s += cnt[blk * N_DEL + d]; }
        off[N_DEL] = s;
    }
    __syncthreads();
    // stage records d-major into LDS; non-temporal (read-once stream, keep L2
    // for the 128x-reused hist segments)
    for (int d = 0; d < N_DEL; ++d) {
        const unsigned long long* R =
            (const unsigned long long*)(recs + ((size_t)blk * N_DEL + d) * CAP);
        int base = off[d], n = off[d + 1] - base;
        for (int k = tid; k < n; k += 256) {
            unsigned long long v = __builtin_nontemporal_load(&R[k]);
            Lrec[base + k] = make_uint2((unsigned)v, (unsigned)(v >> 32));
        }
    }
    int d0 = wv * 2, d1 = wv * 2 + 1;
    int dl0 = __builtin_amdgcn_readfirstlane(delays[d0]);
    int dl1 = __builtin_amdgcn_readfirstlane(delays[d1]);
    float pn = p[blk];
    float pd = (pn < 0.f) ? 1.f : 0.f;
    int q  = lane >> 4;              // 0..3 : which record in the quad
    int bq = lane & 15;              // b-quad index
    __syncthreads();

#pragma unroll
    for (int sidx = 0; sidx < 2; ++sidx) {
        int s = t0 + sidx;
        // ---- GEMM(s): this wave's two delay segments, quarter-wave float4
        float4 acc = make_float4(0.f, 0.f, 0.f, 0.f);
#pragma unroll
        for (int seg = 0; seg < 2; ++seg) {
            int d   = seg ? d1 : d0;
            int dl  = seg ? dl1 : dl0;
            int tau = s - 1 - dl;
            if (tau >= 0) {
                const float* hb = histc + (size_t)(tau % HSLOTS) * NB;
                int kb = off[d], ke = off[d + 1];   // multiples of 4
                for (int k = kb; k + 8 <= ke; k += 8) {
                    uint2 r0 = Lrec[k + q];          // broadcast per 16-lane group
                    uint2 r1 = Lrec[k + 4 + q];
                    float4 v0 = *((const float4*)(hb + r0.y) + bq);
                    float4 v1 = *((const float4*)(hb + r1.y) + bq);
                    float g0 = __uint_as_float(r0.x);
                    float g1 = __uint_as_float(r1.x);
                    acc.x = fmaf(g0, v0.x, acc.x); acc.y = fmaf(g0, v0.y, acc.y);
                    acc.z = fmaf(g0, v0.z, acc.z); acc.w = fmaf(g0, v0.w, acc.w);
                    acc.x = fmaf(g1, v1.x, acc.x); acc.y = fmaf(g1, v1.y, acc.y);
                    acc.z = fmaf(g1, v1.z, acc.z); acc.w = fmaf(g1, v1.w, acc.w);
                }
                if ((ke - kb) & 4) {                 // one leftover quad
                    int k = ke - 4;
                    uint2 r = Lrec[k + q];
                    float4 v = *((const float4*)(hb + r.y) + bq);
                    float g = __uint_as_float(r.x);
                    acc.x = fmaf(g, v.x, acc.x); acc.y = fmaf(g, v.y, acc.y);
                    acc.z = fmaf(g, v.z, acc.z); acc.w = fmaf(g, v.w, acc.w);
                }
            }
        }
        // reduce across q (lane bits 4,5); lanes 0..15 then hold b = bq*4+j
        acc.x += __shfl_xor(acc.x, 16); acc.x += __shfl_xor(acc.x, 32);
        acc.y += __shfl_xor(acc.y, 16); acc.y += __shfl_xor(acc.y, 32);
        acc.z += __shfl_xor(acc.z, 16); acc.z += __shfl_xor(acc.z, 32);
        acc.w += __shfl_xor(acc.w, 16); acc.w += __shfl_xor(acc.w, 32);
        if (lane < 16) *((float4*)&Lg[wv * 64 + lane * 4]) = acc;
        // ---- h1(s) partial: c in [wv*64, wv*64+64)
        {
            float hp = 0.f;
            const float* ib = inpT + (size_t)s * (N_INP * 64)
                            + (size_t)(wv * 64) * 64 + lane;
            const float* wr = w_inT + blk * N_INP + wv * 64;   // uniform -> s_load
#pragma unroll 8
            for (int c2 = 0; c2 < 64; ++c2)
                hp = fmaf(ib[(size_t)c2 * 64], wr[c2], hp);
            Lp[wv * 64 + lane] = hp;
        }
        __syncthreads();
        // ---- pointwise(s): intra-block, wave 0
        if (wv == 0) {
            float syn = Lg[lane] + Lg[64 + lane] + Lg[128 + lane] + Lg[192 + lane];
            float h1  = Lp[lane] + Lp[64 + lane] + Lp[128 + lane] + Lp[192 + lane];
            int i = blk * 64 + lane;
            float m = mem[i];
            float w = wp_arr[i];
            float out = (m - 1.f > 0.f) ? 1.f : 0.f;
            w = w * 0.95f + out * pn * (1.f + pd * w);
            wp_arr[i] = w;
            histc[(size_t)(s % HSLOTS) * NB + i] = out * (1.f + w);
            mem[i] = 0.9f * m + h1 + syn - out;
            unsigned long long mask = __ballot(out > 0.f);
            if (lane == 0) spk[(size_t)s * N_NEUR + blk] = mask;
        }
        __syncthreads();   // Lg/Lp reuse in next sidx
    }
}

// ---------------------------------------------------------------------------
// h2[t][b][o] = sum_n spk_bit(t,n,b) * w_out[n][o]
__global__ __launch_bounds__(256) void h2_gemm(const unsigned long long* __restrict__ spk,
                                               const float* __restrict__ w_out,
                                               float* __restrict__ h2) {
    int t = blockIdx.x;
    int lane = threadIdx.x & 63;     // = b
    int wv   = threadIdx.x >> 6;
    int o0 = wv * 8;
    float acc[8];
#pragma unroll
    for (int j = 0; j < 8; ++j) acc[j] = 0.f;
    for (int n = 0; n < N_NEUR; ++n) {
        unsigned long long mask = spk[(size_t)t * N_NEUR + n];   // uniform
        float s = (float)((mask >> lane) & 1ULL);
        const float* wr = w_out + n * N_OUTC + o0;               // uniform
#pragma unroll
        for (int j = 0; j < 8; ++j) acc[j] = fmaf(s, wr[j], acc[j]);
    }
#pragma unroll
    for (int j = 0; j < 8; ++j)
        h2[((size_t)t * BATCH + lane) * N_OUTC + o0 + j] = acc[j];
}

// out[b][t][o] : leaky-integrator scan over h2
__global__ __launch_bounds__(256) void out_scan(const float* __restrict__ h2,
                                                float* __restrict__ out) {
    int tid = blockIdx.x * 256 + threadIdx.x;   // 2048 = 64b * 32o
    int o = tid & 31;
    int b = tid >> 5;
    float acc = 0.f;
    for (int t = 0; t < T_STEPS; ++t) {
        acc = 0.9f * acc + h2[((size_t)t * BATCH + b) * N_OUTC + o];
        out[((size_t)b * T_STEPS + t) * N_OUTC + o] = acc;
    }
}

// ---------------------------------------------------------------------------
extern "C" void kernel_launch(void* const* d_in, const int* in_sizes, int n_in,
                              void* d_out, int out_size, void* d_ws, size_t ws_size,
                              hipStream_t stream) {
    (void)in_sizes; (void)n_in; (void)out_size; (void)ws_size;
    const float* inputs = (const float*)d_in[0];
    const float* w      = (const float*)d_in[1];
    const float* w_in   = (const float*)d_in[2];
    const float* w_out  = (const float*)d_in[3];
    const float* signs  = (const float*)d_in[4];
    const float* p      = (const float*)d_in[5];
    const float* dmap   = (const float*)d_in[6];
    const int*   delays = (const int*)d_in[7];
    float* out = (float*)d_out;

    // workspace layout (~97 MiB total, well under proven 120.6 MiB)
    float* ws    = (float*)d_ws;
    float* inpT  = ws;                                    //  8,192,000 f
    float* w_inT = inpT + (size_t)T_STEPS * N_INP * 64;   //    262,144 f
    float* histc = w_inT + (size_t)N_NEUR * N_INP;        //  8,519,680 f
    float* mem   = histc + (size_t)HSLOTS * NB;           //     65,536 f
    float* wp    = mem + NB;                              //     65,536 f
    float* h2    = wp + NB;                               //  1,024,000 f
    int*   cnt   = (int*)(h2 + (size_t)T_STEPS * BATCH * N_OUTC);  // 8192 i
    uint2* recs  = (uint2*)(cnt + N_NEUR * N_DEL);        //  2,621,440 uint2
    unsigned long long* spk =
        (unsigned long long*)(recs + (size_t)N_NEUR * N_DEL * CAP); // 512,000 ull

    hipMemsetAsync(histc, 0, sizeof(float) * (size_t)HSLOTS * NB, stream);
    hipMemsetAsync(mem, 0, sizeof(float) * (size_t)2 * NB, stream);  // mem+wp adjacent

    transpose_inp<<<T_STEPS, 256, 0, stream>>>(inputs, inpT);
    transpose_win<<<(N_NEUR * N_INP) / 256, 256, 0, stream>>>(w_in, w_inT);
    build_csr<<<16, 64, 0, stream>>>(w, signs, dmap, recs, cnt);

    for (int t0 = 0; t0 < T_STEPS; t0 += 2)
        step_pair<<<N_NEUR, 256, 0, stream>>>(t0, recs, cnt, delays, inpT,
                                              w_inT, p, histc, mem, wp, spk);

    h2_gemm<<<T_STEPS, 256, 0, stream>>>(spk, w_out, h2);
    out_scan<<<8, 256, 0, stream>>>(h2, out);
}

// Round 9
// 12135.585 us; speedup vs baseline: 7.4051x; 1.0478x over previous
//
#include <hip/hip_runtime.h>
#include <stdint.h>

#define N_NEUR  1024
#define N_INP   256
#define N_OUTC  32
#define T_STEPS 500
#define BATCH   64
#define N_DEL   8
#define NB      (N_NEUR*BATCH)     // 65536, layout [n][b], b fastest
#define HSLOTS  132                // ring: live window is 131 steps (writes t0,t0+1;
                                   // reads t0-129..t0-1) -> 132 proves no aliasing.
                                   // 130 RACED (slot(s-129)==slot(s+1)) - round 8 bug.
#define CAP     256                // per-(o,d) record capacity (mean 128, 12 sigma)
#define H1RING  64                 // h1 ring depth (steps), power of 2
#define LREC_MAX 1152              // >= 1024 + 8*3 padding

// ---------------------------------------------------------------------------
// inpT[t][c][b] = inputs[b][t][c]
__global__ __launch_bounds__(256) void transpose_inp(const float* __restrict__ inp,
                                                     float* __restrict__ inpT) {
    __shared__ float L[N_INP * 64];
    int t = blockIdx.x;
    int tid = threadIdx.x;                   // = c
    for (int b = 0; b < 64; ++b) {
        float v = inp[((size_t)b * T_STEPS + t) * N_INP + tid];
        L[tid * 64 + (b ^ (tid & 63))] = v;
    }
    __syncthreads();
    int lane = tid & 63;
    int wv   = tid >> 6;
    for (int cc = 0; cc < 64; ++cc) {
        int c = cc * 4 + wv;
        inpT[((size_t)t * N_INP + c) * 64 + lane] = L[c * 64 + (lane ^ (c & 63))];
    }
}

// w_inT[n][c] = w_in[c][n]
__global__ __launch_bounds__(256) void transpose_win(const float* __restrict__ w_in,
                                                     float* __restrict__ w_inT) {
    int i = blockIdx.x * 256 + threadIdx.x;  // 262144
    int n = i >> 8, c = i & 255;
    w_inT[i] = w_in[(size_t)c * N_NEUR + n];
}

// ---------------------------------------------------------------------------
// CSR build: for each (o,d), list of {G = sign[e]*|w[e][o]|, e*64} where
// dmap[d][e][o] == 1. Padded to a multiple of 4 with zero-records (G=0 -> inert).
__global__ __launch_bounds__(64) void build_csr(const float* __restrict__ w,
                                                const float* __restrict__ signs,
                                                const float* __restrict__ dmap,
                                                uint2* __restrict__ recs,
                                                int* __restrict__ cnt) {
    int o = blockIdx.x * 64 + threadIdx.x;   // 16 blocks x 64 lanes
    for (int d = 0; d < N_DEL; ++d) {
        int c = 0;
        uint2* seg = recs + ((size_t)o * N_DEL + d) * CAP;
        for (int e = 0; e < N_NEUR; ++e) {
            float m = dmap[((size_t)d * N_NEUR + e) * N_NEUR + o];  // coalesced over o
            if (m != 0.f) {
                float G = signs[e] * fabsf(w[(size_t)e * N_NEUR + o]);
                if (c < CAP) seg[c] = make_uint2(__float_as_uint(G), (unsigned)(e * 64));
                ++c;
            }
        }
        if (c > CAP) c = CAP;
        int c4 = (c + 3) & ~3;                // pad to multiple of 4
        for (; c < c4; ++c) seg[c] = make_uint2(0u, 0u);
        cnt[o * N_DEL + d] = c4;
    }
}

// ---------------------------------------------------------------------------
// h1 ring precompute, 64 steps per launch (bit-exact vs the round-7 in-step
// code: same per-wave c-split, same fma order, same 4-partial reduce).
__global__ __launch_bounds__(256) void h1_chunk(int t0,
        const float* __restrict__ inpT, const float* __restrict__ w_inT,
        float* __restrict__ h1r) {
    __shared__ float Li[N_INP * 64];   // 64 KB
    __shared__ float Lp[4 * 64];
    int s     = t0 + blockIdx.x;
    int ntile = blockIdx.y;            // 16 tiles x 64 n
    int tid   = threadIdx.x;
    int lane  = tid & 63;
    int wv    = tid >> 6;
    const float4* src = (const float4*)(inpT + (size_t)s * (N_INP * 64));
    float4* dst = (float4*)Li;
    for (int k = tid; k < (N_INP * 64) / 4; k += 256) dst[k] = src[k];
    __syncthreads();
    for (int nn = 0; nn < 64; ++nn) {
        int n = ntile * 64 + nn;
        float hp = 0.f;
        const float* wr = w_inT + n * N_INP + wv * 64;   // uniform -> s_load
#pragma unroll 8
        for (int c2 = 0; c2 < 64; ++c2)
            hp = fmaf(Li[(wv * 64 + c2) * 64 + lane], wr[c2], hp);
        Lp[wv * 64 + lane] = hp;
        __syncthreads();
        if (wv == 0)
            h1r[(size_t)(s & (H1RING - 1)) * NB + n * 64 + lane] =
                Lp[lane] + Lp[64 + lane] + Lp[128 + lane] + Lp[192 + lane];
        __syncthreads();
    }
}

// ---------------------------------------------------------------------------
// Two simulation steps per launch. Block = o (GEMM) = n (pointwise). Both
// steps' GEMMs are fused in one record pass: one LDS record read feeds two
// gathers (slots tau and tau+1) -> 2x MLP, half the loop/LDS overhead.
// All hist reads are pre-launch (ages 2..129 for s0, 1+..128+1 for s1 ->
// steps <= t0-1); writes are steps t0,t0+1 -> HSLOTS=132 proves disjoint.
__global__ __launch_bounds__(256) void step_pair(int t0,
        const uint2* __restrict__ recs, const int* __restrict__ cnt,
        const int* __restrict__ delays, const float* __restrict__ h1r,
        const float* __restrict__ p,
        float* __restrict__ histc, float* __restrict__ mem,
        float* __restrict__ wp_arr, unsigned long long* __restrict__ spk) {
    __shared__ uint2 Lrec[LREC_MAX]; // ~9 KB: this o's record list, d-major, padded
    __shared__ int   off[N_DEL + 1];
    __shared__ float Lg0[4 * 64];    // GEMM partials step t0
    __shared__ float Lg1[4 * 64];    // GEMM partials step t0+1
    int blk  = blockIdx.x;           // o = n
    int tid  = threadIdx.x;
    int lane = tid & 63;             // b
    int wv   = __builtin_amdgcn_readfirstlane(tid >> 6);

    if (tid == 0) {
        int s = 0;
        for (int d = 0; d < N_DEL; ++d) { off[d] = s; s += cnt[blk * N_DEL + d]; }
        off[N_DEL] = s;
    }
    __syncthreads();
    // stage records d-major into LDS; non-temporal (read-once stream)
    for (int d = 0; d < N_DEL; ++d) {
        const unsigned long long* R =
            (const unsigned long long*)(recs + ((size_t)blk * N_DEL + d) * CAP);
        int base = off[d], n = off[d + 1] - base;
        for (int k = tid; k < n; k += 256) {
            unsigned long long v = __builtin_nontemporal_load(&R[k]);
            Lrec[base + k] = make_uint2((unsigned)v, (unsigned)(v >> 32));
        }
    }
    int d0 = wv * 2, d1 = wv * 2 + 1;
    int dl0 = __builtin_amdgcn_readfirstlane(delays[d0]);
    int dl1 = __builtin_amdgcn_readfirstlane(delays[d1]);
    float pn = p[blk];
    float pd = (pn < 0.f) ? 1.f : 0.f;
    int q  = lane >> 4;              // 0..3 : which record in the quad
    int bq = lane & 15;              // b-quad index
    __syncthreads();

    float4 acc0 = make_float4(0.f, 0.f, 0.f, 0.f);   // step t0
    float4 acc1 = make_float4(0.f, 0.f, 0.f, 0.f);   // step t0+1
#pragma unroll
    for (int seg = 0; seg < 2; ++seg) {
        int d    = seg ? d1 : d0;
        int dl   = seg ? dl1 : dl0;
        int tau0 = t0 - 1 - dl;          // step t0 read
        int tau1 = tau0 + 1;             // step t0+1 read
        int kb = off[d], ke = off[d + 1];   // multiples of 4
        if (tau0 >= 0) {
            // both steps valid: fused dual gather
            const float* hb0 = histc + (size_t)(tau0 % HSLOTS) * NB;
            const float* hb1 = histc + (size_t)(tau1 % HSLOTS) * NB;
            int k = kb;
            for (; k + 8 <= ke; k += 8) {
                uint2 ra = Lrec[k + q];
                uint2 rb = Lrec[k + 4 + q];
                float ga = __uint_as_float(ra.x);
                float gb = __uint_as_float(rb.x);
                float4 a0 = *((const float4*)(hb0 + ra.y) + bq);
                float4 a1 = *((const float4*)(hb1 + ra.y) + bq);
                float4 b0 = *((const float4*)(hb0 + rb.y) + bq);
                float4 b1 = *((const float4*)(hb1 + rb.y) + bq);
                acc0.x = fmaf(ga, a0.x, acc0.x); acc0.y = fmaf(ga, a0.y, acc0.y);
                acc0.z = fmaf(ga, a0.z, acc0.z); acc0.w = fmaf(ga, a0.w, acc0.w);
                acc1.x = fmaf(ga, a1.x, acc1.x); acc1.y = fmaf(ga, a1.y, acc1.y);
                acc1.z = fmaf(ga, a1.z, acc1.z); acc1.w = fmaf(ga, a1.w, acc1.w);
                acc0.x = fmaf(gb, b0.x, acc0.x); acc0.y = fmaf(gb, b0.y, acc0.y);
                acc0.z = fmaf(gb, b0.z, acc0.z); acc0.w = fmaf(gb, b0.w, acc0.w);
                acc1.x = fmaf(gb, b1.x, acc1.x); acc1.y = fmaf(gb, b1.y, acc1.y);
                acc1.z = fmaf(gb, b1.z, acc1.z); acc1.w = fmaf(gb, b1.w, acc1.w);
            }
            if ((ke - kb) & 4) {
                uint2 r = Lrec[ke - 4 + q];
                float g = __uint_as_float(r.x);
                float4 a0 = *((const float4*)(hb0 + r.y) + bq);
                float4 a1 = *((const float4*)(hb1 + r.y) + bq);
                acc0.x = fmaf(g, a0.x, acc0.x); acc0.y = fmaf(g, a0.y, acc0.y);
                acc0.z = fmaf(g, a0.z, acc0.z); acc0.w = fmaf(g, a0.w, acc0.w);
                acc1.x = fmaf(g, a1.x, acc1.x); acc1.y = fmaf(g, a1.y, acc1.y);
                acc1.z = fmaf(g, a1.z, acc1.z); acc1.w = fmaf(g, a1.w, acc1.w);
            }
        } else if (tau1 >= 0) {          // only step t0+1 reads (tau0 == -1)
            const float* hb1 = histc + (size_t)(tau1 % HSLOTS) * NB;
            for (int k = kb; k + 4 <= ke; k += 4) {
                uint2 r = Lrec[k + q];
                float g = __uint_as_float(r.x);
                float4 a1 = *((const float4*)(hb1 + r.y) + bq);
                acc1.x = fmaf(g, a1.x, acc1.x); acc1.y = fmaf(g, a1.y, acc1.y);
                acc1.z = fmaf(g, a1.z, acc1.z); acc1.w = fmaf(g, a1.w, acc1.w);
            }
        }
    }
    // reduce across q (lane bits 4,5); lanes 0..15 then hold b = bq*4+j
    acc0.x += __shfl_xor(acc0.x, 16); acc0.x += __shfl_xor(acc0.x, 32);
    acc0.y += __shfl_xor(acc0.y, 16); acc0.y += __shfl_xor(acc0.y, 32);
    acc0.z += __shfl_xor(acc0.z, 16); acc0.z += __shfl_xor(acc0.z, 32);
    acc0.w += __shfl_xor(acc0.w, 16); acc0.w += __shfl_xor(acc0.w, 32);
    acc1.x += __shfl_xor(acc1.x, 16); acc1.x += __shfl_xor(acc1.x, 32);
    acc1.y += __shfl_xor(acc1.y, 16); acc1.y += __shfl_xor(acc1.y, 32);
    acc1.z += __shfl_xor(acc1.z, 16); acc1.z += __shfl_xor(acc1.z, 32);
    acc1.w += __shfl_xor(acc1.w, 16); acc1.w += __shfl_xor(acc1.w, 32);
    if (lane < 16) {
        *((float4*)&Lg0[wv * 64 + lane * 4]) = acc0;
        *((float4*)&Lg1[wv * 64 + lane * 4]) = acc1;
    }
    __syncthreads();
    // ---- pointwise(t0) then pointwise(t0+1): intra-block, wave 0
    if (wv == 0) {
        int i = blk * 64 + lane;
        float m = mem[i];
        float w = wp_arr[i];
#pragma unroll
        for (int sidx = 0; sidx < 2; ++sidx) {
            int s = t0 + sidx;
            const float* Lg = sidx ? Lg1 : Lg0;
            float syn = Lg[lane] + Lg[64 + lane] + Lg[128 + lane] + Lg[192 + lane];
            float h1 = h1r[(size_t)(s & (H1RING - 1)) * NB + i];
            float out = (m - 1.f > 0.f) ? 1.f : 0.f;
            w = w * 0.95f + out * pn * (1.f + pd * w);
            histc[(size_t)(s % HSLOTS) * NB + i] = out * (1.f + w);
            m = 0.9f * m + h1 + syn - out;
            unsigned long long mask = __ballot(out > 0.f);
            if (lane == 0) spk[(size_t)s * N_NEUR + blk] = mask;
        }
        mem[i] = m;
        wp_arr[i] = w;
    }
}

// ---------------------------------------------------------------------------
// h2[t][b][o] = sum_n spk_bit(t,n,b) * w_out[n][o]
__global__ __launch_bounds__(256) void h2_gemm(const unsigned long long* __restrict__ spk,
                                               const float* __restrict__ w_out,
                                               float* __restrict__ h2) {
    int t = blockIdx.x;
    int lane = threadIdx.x & 63;     // = b
    int wv   = threadIdx.x >> 6;
    int o0 = wv * 8;
    float acc[8];
#pragma unroll
    for (int j = 0; j < 8; ++j) acc[j] = 0.f;
    for (int n = 0; n < N_NEUR; ++n) {
        unsigned long long mask = spk[(size_t)t * N_NEUR + n];   // uniform
        float s = (float)((mask >> lane) & 1ULL);
        const float* wr = w_out + n * N_OUTC + o0;               // uniform
#pragma unroll
        for (int j = 0; j < 8; ++j) acc[j] = fmaf(s, wr[j], acc[j]);
    }
#pragma unroll
    for (int j = 0; j < 8; ++j)
        h2[((size_t)t * BATCH + lane) * N_OUTC + o0 + j] = acc[j];
}

// out[b][t][o] : leaky-integrator scan over h2
__global__ __launch_bounds__(256) void out_scan(const float* __restrict__ h2,
                                                float* __restrict__ out) {
    int tid = blockIdx.x * 256 + threadIdx.x;   // 2048 = 64b * 32o
    int o = tid & 31;
    int b = tid >> 5;
    float acc = 0.f;
    for (int t = 0; t < T_STEPS; ++t) {
        acc = 0.9f * acc + h2[((size_t)t * BATCH + b) * N_OUTC + o];
        out[((size_t)b * T_STEPS + t) * N_OUTC + o] = acc;
    }
}

// ---------------------------------------------------------------------------
extern "C" void kernel_launch(void* const* d_in, const int* in_sizes, int n_in,
                              void* d_out, int out_size, void* d_ws, size_t ws_size,
                              hipStream_t stream) {
    (void)in_sizes; (void)n_in; (void)out_size; (void)ws_size;
    const float* inputs = (const float*)d_in[0];
    const float* w      = (const float*)d_in[1];
    const float* w_in   = (const float*)d_in[2];
    const float* w_out  = (const float*)d_in[3];
    const float* signs  = (const float*)d_in[4];
    const float* p      = (const float*)d_in[5];
    const float* dmap   = (const float*)d_in[6];
    const int*   delays = (const int*)d_in[7];
    float* out = (float*)d_out;

    // workspace layout (~106 MiB total, under proven 120.6 MiB)
    float* ws    = (float*)d_ws;
    float* inpT  = ws;                                    //  8,192,000 f
    float* w_inT = inpT + (size_t)T_STEPS * N_INP * 64;   //    262,144 f
    float* histc = w_inT + (size_t)N_NEUR * N_INP;        //  8,650,752 f
    float* h1r   = histc + (size_t)HSLOTS * NB;           //  4,194,304 f
    float* mem   = h1r + (size_t)H1RING * NB;             //     65,536 f
    float* wp    = mem + NB;                              //     65,536 f
    float* h2    = wp + NB;                               //  1,024,000 f
    int*   cnt   = (int*)(h2 + (size_t)T_STEPS * BATCH * N_OUTC);  // 8192 i
    uint2* recs  = (uint2*)(cnt + N_NEUR * N_DEL);        //  2,097,152 uint2
    unsigned long long* spk =
        (unsigned long long*)(recs + (size_t)N_NEUR * N_DEL * CAP); // 512,000 ull

    hipMemsetAsync(histc, 0, sizeof(float) * (size_t)HSLOTS * NB, stream);
    hipMemsetAsync(mem, 0, sizeof(float) * (size_t)2 * NB, stream);  // mem+wp adjacent

    transpose_inp<<<T_STEPS, 256, 0, stream>>>(inputs, inpT);
    transpose_win<<<(N_NEUR * N_INP) / 256, 256, 0, stream>>>(w_in, w_inT);
    build_csr<<<16, 64, 0, stream>>>(w, signs, dmap, recs, cnt);

    for (int t0 = 0; t0 < T_STEPS; t0 += 2) {
        if ((t0 & (H1RING - 1)) == 0) {
            int ns = T_STEPS - t0; if (ns > H1RING) ns = H1RING;
            h1_chunk<<<dim3(ns, 16), 256, 0, stream>>>(t0, inpT, w_inT, h1r);
        }
        step_pair<<<N_NEUR, 256, 0, stream>>>(t0, recs, cnt, delays, h1r, p,
                                              histc, mem, wp, spk);
    }

    h2_gemm<<<T_STEPS, 256, 0, stream>>>(spk, w_out, h2);
    out_scan<<<8, 256, 0, stream>>>(h2, out);
}